// Round 1
// baseline (2838.648 us; speedup 1.0000x reference)
//
#include <hip/hip_runtime.h>

#define N_NODES 100000
#define N_EDGES 800000
#define N_GRAPH 512
#define HD 64
#define MSGD 128
#define NODE_IN 92
#define EDGE_IN 16
#define NLAYER 3

// ---------------------------------------------------------------------------
// Node embedding: h[n][j] = relu(x[n] @ node_w + node_b), K=92, 16 nodes/block
// ---------------------------------------------------------------------------
__global__ __launch_bounds__(256)
void node_embed_kernel(const float* __restrict__ x, const float* __restrict__ nw,
                       const float* __restrict__ nb, float* __restrict__ hout)
{
    __shared__ float s_x[16 * NODE_IN];
    const int t = threadIdx.x;
    const int j = t & 63, iq = t >> 6;
    const int n0 = blockIdx.x * 16;

    for (int idx = t; idx < 16 * NODE_IN; idx += 256)
        s_x[idx] = x[(size_t)n0 * NODE_IN + idx];
    __syncthreads();

    float acc[4];
    const float bj = nb[j];
#pragma unroll
    for (int q = 0; q < 4; ++q) acc[q] = bj;

#pragma unroll 4
    for (int k = 0; k < NODE_IN; ++k) {
        float wv = nw[k * 64 + j];
#pragma unroll
        for (int q = 0; q < 4; ++q)
            acc[q] += s_x[(iq + q * 4) * NODE_IN + k] * wv;
    }
#pragma unroll
    for (int q = 0; q < 4; ++q) {
        int n = n0 + iq + q * 4;
        hout[(size_t)n * 64 + j] = fmaxf(acc[q], 0.f);
    }
}

// ---------------------------------------------------------------------------
// Edge MLP + scatter-add (one layer). 64-edge tiles, grid-stride.
// LDS: w1^T (64KB, swizzled) + w2^T (32KB, swizzled) + m_in/hidden (32KB) + misc
// ---------------------------------------------------------------------------
__global__ __launch_bounds__(256, 1)
void edge_mlp_kernel(const float* __restrict__ h,
                     const int* __restrict__ src_idx,
                     const int* __restrict__ dst_idx,
                     const float* __restrict__ eattr,
                     const float* __restrict__ we, const float* __restrict__ be,
                     const float* __restrict__ w1, const float* __restrict__ b1,
                     const float* __restrict__ w2, const float* __restrict__ b2,
                     float* __restrict__ agg)
{
    __shared__ float s_w1[128 * 128];   // [j][k] swizzled
    __shared__ float s_w2[64 * 128];    // [j][k] swizzled
    __shared__ float s_mi[64 * 128];    // m_in tile, reused as hidden tile
    __shared__ float s_we[16 * 64];
    __shared__ float s_ea[64 * 16];
    __shared__ float s_b1[128];
    __shared__ float s_b2[64];
    __shared__ float s_be[64];
    __shared__ int   s_src[64];
    __shared__ int   s_dst[64];

    const int t = threadIdx.x;

    // ---- preload weights (once per block) ----
    for (int idx = t; idx < 128 * 128; idx += 256) {
        int k = idx >> 7, j = idx & 127;
        s_w1[j * 128 + (((((k >> 2) ^ (j & 15))) << 2) | (k & 3))] = w1[idx];
    }
    for (int idx = t; idx < 128 * 64; idx += 256) {
        int k = idx >> 6, j = idx & 63;
        s_w2[j * 128 + (((((k >> 2) ^ (j & 15))) << 2) | (k & 3))] = w2[idx];
    }
    for (int idx = t; idx < 16 * 64; idx += 256) s_we[idx] = we[idx];
    if (t < 128) s_b1[t] = b1[t];
    if (t < 64) { s_b2[t] = b2[t]; s_be[t] = be[t]; }
    __syncthreads();

    const int tx = t & 15, ty = t >> 4;   // compute mapping
    const int el = t >> 2, part = t & 3;  // staging mapping

    for (int tile = blockIdx.x; tile < N_EDGES / 64; tile += gridDim.x) {
        const int e0 = tile * 64;

        // ---- stage indices + raw edge_attr ----
        if (t < 64) { s_src[t] = src_idx[e0 + t]; s_dst[t] = dst_idx[e0 + t]; }
        {
            float4 v = *(const float4*)(eattr + (size_t)e0 * 16 + t * 4);
            *(float4*)(s_ea + t * 4) = v;
        }
        __syncthreads();

        // ---- gather h rows into m_in cols [0,64) (swizzled) ----
        {
            const int sn = s_src[el];
            const float* hp = h + (size_t)sn * 64 + part * 16;
#pragma unroll
            for (int c = 0; c < 4; ++c) {
                float4 v = *(const float4*)(hp + c * 4);
                int k4 = part * 4 + c;
                *(float4*)(s_mi + el * 128 + ((k4 ^ (el & 15)) << 2)) = v;
            }
        }
        // ---- compute edge embedding into m_in cols [64,128) ----
        {
#pragma unroll
            for (int jj = 0; jj < 16; ++jj) {
                int j = part * 16 + jj;
                float acc = s_be[j];
#pragma unroll
                for (int k = 0; k < 16; ++k)
                    acc += s_ea[el * 16 + k] * s_we[k * 64 + j];
                acc = fmaxf(acc, 0.f);
                int col = 64 + j;
                s_mi[el * 128 + (((((col >> 2) ^ (el & 15))) << 2) | (col & 3))] = acc;
            }
        }
        __syncthreads();

        // ---- phase A: hidden[e][j] = relu(m_in @ w1 + b1), 4 edges x 8 j/thread
        float hid[4][8];
#pragma unroll
        for (int i = 0; i < 4; ++i)
#pragma unroll
            for (int u = 0; u < 8; ++u)
                hid[i][u] = s_b1[u * 16 + tx];

#pragma unroll 2
        for (int k4 = 0; k4 < 32; ++k4) {
            float4 a[4], b[8];
#pragma unroll
            for (int i = 0; i < 4; ++i) {
                int e = ty * 4 + i;
                a[i] = *(const float4*)(s_mi + e * 128 + ((k4 ^ (e & 15)) << 2));
            }
#pragma unroll
            for (int u = 0; u < 8; ++u) {
                int j = u * 16 + tx;
                b[u] = *(const float4*)(s_w1 + j * 128 + ((k4 ^ (j & 15)) << 2));
            }
#pragma unroll
            for (int i = 0; i < 4; ++i)
#pragma unroll
                for (int u = 0; u < 8; ++u)
                    hid[i][u] += a[i].x * b[u].x + a[i].y * b[u].y +
                                 a[i].z * b[u].z + a[i].w * b[u].w;
        }
        __syncthreads();   // all phase-A reads of s_mi complete

        // ---- write relu(hidden) back into s_mi (as [e][k=128], swizzled) ----
#pragma unroll
        for (int i = 0; i < 4; ++i) {
            int e = ty * 4 + i;
#pragma unroll
            for (int u = 0; u < 8; ++u) {
                int j = u * 16 + tx;
                s_mi[e * 128 + (((((j >> 2) ^ (e & 15))) << 2) | (j & 3))] =
                    fmaxf(hid[i][u], 0.f);
            }
        }
        __syncthreads();

        // ---- phase B: m[e][j] = hidden @ w2 + b2, 4 edges x 4 j/thread ----
        float m[4][4];
#pragma unroll
        for (int i = 0; i < 4; ++i)
#pragma unroll
            for (int u = 0; u < 4; ++u)
                m[i][u] = s_b2[u * 16 + tx];

#pragma unroll 2
        for (int k4 = 0; k4 < 32; ++k4) {
            float4 a[4], b[4];
#pragma unroll
            for (int i = 0; i < 4; ++i) {
                int e = ty * 4 + i;
                a[i] = *(const float4*)(s_mi + e * 128 + ((k4 ^ (e & 15)) << 2));
            }
#pragma unroll
            for (int u = 0; u < 4; ++u) {
                int j = u * 16 + tx;
                b[u] = *(const float4*)(s_w2 + j * 128 + ((k4 ^ (j & 15)) << 2));
            }
#pragma unroll
            for (int i = 0; i < 4; ++i)
#pragma unroll
                for (int u = 0; u < 4; ++u)
                    m[i][u] += a[i].x * b[u].x + a[i].y * b[u].y +
                               a[i].z * b[u].z + a[i].w * b[u].w;
        }

        // ---- scatter-add into agg ----
#pragma unroll
        for (int i = 0; i < 4; ++i) {
            int e = ty * 4 + i;
            int d = s_dst[e];
            float* ap = agg + (size_t)d * 64;
#pragma unroll
            for (int u = 0; u < 4; ++u)
                atomicAdd(ap + u * 16 + tx, m[i][u]);
        }
        __syncthreads();   // protect s_mi/s_ea/s_src for next tile
    }
}

// ---------------------------------------------------------------------------
// Self update: h2 = relu(agg + h @ self_w + self_b), 16 nodes/block
// ---------------------------------------------------------------------------
__global__ __launch_bounds__(256)
void self_update_kernel(const float* __restrict__ hin, const float* __restrict__ agg,
                        const float* __restrict__ sw, const float* __restrict__ sb,
                        float* __restrict__ hout)
{
    __shared__ float s_h[16 * 64];
    const int t = threadIdx.x;
    const int j = t & 63, iq = t >> 6;
    const int n0 = blockIdx.x * 16;

    for (int idx = t; idx < 16 * 64; idx += 256)
        s_h[idx] = hin[(size_t)n0 * 64 + idx];
    __syncthreads();

    float acc[4];
    const float bj = sb[j];
#pragma unroll
    for (int q = 0; q < 4; ++q) acc[q] = bj;

#pragma unroll 4
    for (int k = 0; k < 64; ++k) {
        float wv = sw[k * 64 + j];
#pragma unroll
        for (int q = 0; q < 4; ++q)
            acc[q] += s_h[(iq + q * 4) * 64 + k] * wv;
    }
#pragma unroll
    for (int q = 0; q < 4; ++q) {
        int n = n0 + iq + q * 4;
        float v = acc[q] + agg[(size_t)n * 64 + j];
        hout[(size_t)n * 64 + j] = fmaxf(v, 0.f);
    }
}

// ---------------------------------------------------------------------------
// Graph pooling: gsum[b][j] += h[n][j], counts[b] += 1; batch sorted -> run-
// length pre-reduction over 32-node chunks before atomics.
// ---------------------------------------------------------------------------
__global__ __launch_bounds__(256)
void pool_kernel(const float* __restrict__ h, const int* __restrict__ batch,
                 float* __restrict__ gsum, float* __restrict__ counts)
{
    const int t = threadIdx.x;
    const int j = t & 63, ty = t >> 6;
    const int grp = blockIdx.x * 4 + ty;
    if (grp >= N_NODES / 32) return;
    const int n0 = grp * 32;

    float acc = 0.f, cnt = 0.f;
    int cur = batch[n0];
    for (int n = n0; n < n0 + 32; ++n) {
        int b = batch[n];
        if (b != cur) {
            atomicAdd(gsum + (size_t)cur * 64 + j, acc);
            if (j == 0) atomicAdd(counts + cur, cnt);
            acc = 0.f; cnt = 0.f; cur = b;
        }
        acc += h[(size_t)n * 64 + j];
        cnt += 1.f;
    }
    atomicAdd(gsum + (size_t)cur * 64 + j, acc);
    if (j == 0) atomicAdd(counts + cur, cnt);
}

// ---------------------------------------------------------------------------
// Readout: out[g] = relu([gsum, gsum/cnt] @ ro_w1 + b1) @ ro_w2 + b2
// ---------------------------------------------------------------------------
__global__ __launch_bounds__(64)
void readout_kernel(const float* __restrict__ gsum, const float* __restrict__ counts,
                    const float* __restrict__ w1, const float* __restrict__ b1,
                    const float* __restrict__ w2, const float* __restrict__ b2,
                    float* __restrict__ out)
{
    __shared__ float s_g[128];
    const int g = blockIdx.x, t = threadIdx.x;
    float sv = gsum[(size_t)g * 64 + t];
    float c = fmaxf(counts[g], 1.f);
    s_g[t] = sv;
    s_g[64 + t] = sv / c;
    __syncthreads();

    float acc = b1[t];
#pragma unroll 4
    for (int k = 0; k < 128; ++k)
        acc += s_g[k] * w1[k * 64 + t];
    acc = fmaxf(acc, 0.f);

    float p = acc * w2[t];
#pragma unroll
    for (int m = 1; m < 64; m <<= 1)
        p += __shfl_xor(p, m, 64);
    if (t == 0) out[g] = p + b2[0];
}

// ---------------------------------------------------------------------------
extern "C" void kernel_launch(void* const* d_in, const int* in_sizes, int n_in,
                              void* d_out, int out_size, void* d_ws, size_t ws_size,
                              hipStream_t stream)
{
    const float* x      = (const float*)d_in[0];
    const int*   eidx   = (const int*)d_in[1];
    const float* eattr  = (const float*)d_in[2];
    const int*   batch  = (const int*)d_in[3];
    const float* node_w = (const float*)d_in[4];
    const float* node_b = (const float*)d_in[5];
    const float* edge_w = (const float*)d_in[6];
    const float* edge_b = (const float*)d_in[7];
    const float* msg_w1 = (const float*)d_in[8];
    const float* msg_b1 = (const float*)d_in[9];
    const float* msg_w2 = (const float*)d_in[10];
    const float* msg_b2 = (const float*)d_in[11];
    const float* self_w = (const float*)d_in[12];
    const float* self_b = (const float*)d_in[13];
    const float* ro_w1  = (const float*)d_in[14];
    const float* ro_b1  = (const float*)d_in[15];
    const float* ro_w2  = (const float*)d_in[16];
    const float* ro_b2  = (const float*)d_in[17];
    float* out = (float*)d_out;

    float* ws     = (float*)d_ws;
    float* h0     = ws;
    float* h1     = ws + (size_t)N_NODES * 64;
    float* agg    = ws + (size_t)2 * N_NODES * 64;
    float* gsum   = ws + (size_t)3 * N_NODES * 64;
    float* counts = gsum + (size_t)N_GRAPH * 64;

    const int* srcp = eidx;
    const int* dstp = eidx + N_EDGES;

    node_embed_kernel<<<N_NODES / 16, 256, 0, stream>>>(x, node_w, node_b, h0);

    float* hc = h0;
    float* hn = h1;
    for (int l = 0; l < NLAYER; ++l) {
        hipMemsetAsync(agg, 0, (size_t)N_NODES * 64 * sizeof(float), stream);
        edge_mlp_kernel<<<256, 256, 0, stream>>>(
            hc, srcp, dstp, eattr, edge_w, edge_b,
            msg_w1 + (size_t)l * 128 * 128, msg_b1 + (size_t)l * 128,
            msg_w2 + (size_t)l * 128 * 64,  msg_b2 + (size_t)l * 64,
            agg);
        self_update_kernel<<<N_NODES / 16, 256, 0, stream>>>(
            hc, agg, self_w + (size_t)l * 64 * 64, self_b + (size_t)l * 64, hn);
        float* tmp = hc; hc = hn; hn = tmp;
    }

    hipMemsetAsync(gsum, 0, (size_t)(N_GRAPH * 64 + N_GRAPH) * sizeof(float), stream);
    pool_kernel<<<(N_NODES / 32 + 3) / 4, 256, 0, stream>>>(hc, batch, gsum, counts);
    readout_kernel<<<N_GRAPH, 64, 0, stream>>>(gsum, counts, ro_w1, ro_b1, ro_w2, ro_b2, out);
}

// Round 2
// 719.722 us; speedup vs baseline: 3.9441x; 3.9441x over previous
//
#include <hip/hip_runtime.h>

#define N_NODES 100000
#define N_EDGES 800000
#define N_GRAPH 512
#define NODE_IN 92
#define NLAYER 3
#define EDGE_GRID 1024

typedef short bf16x8 __attribute__((ext_vector_type(8)));
typedef float f32x4  __attribute__((ext_vector_type(4)));

#define MFMA16(a, b, c) __builtin_amdgcn_mfma_f32_16x16x32_bf16(a, b, c, 0, 0, 0)

__device__ __forceinline__ short f2bf(float f) {
    union { float f; unsigned u; } v; v.f = f;
    unsigned u = v.u;
    unsigned r = (u + 0x7fffu + ((u >> 16) & 1u)) >> 16;
    return (short)r;
}

// ---------------------------------------------------------------------------
// Node embedding: h = relu(x @ node_w + node_b); writes f32 + bf16 copies
// ---------------------------------------------------------------------------
__global__ __launch_bounds__(256)
void node_embed_kernel(const float* __restrict__ x, const float* __restrict__ nw,
                       const float* __restrict__ nb, float* __restrict__ hout,
                       short* __restrict__ hb)
{
    __shared__ float s_x[16 * NODE_IN];
    const int t = threadIdx.x;
    const int j = t & 63, iq = t >> 6;
    const int n0 = blockIdx.x * 16;

    for (int idx = t; idx < 16 * NODE_IN; idx += 256)
        s_x[idx] = x[(size_t)n0 * NODE_IN + idx];
    __syncthreads();

    float acc[4];
    const float bj = nb[j];
#pragma unroll
    for (int q = 0; q < 4; ++q) acc[q] = bj;

#pragma unroll 4
    for (int k = 0; k < NODE_IN; ++k) {
        float wv = nw[k * 64 + j];
#pragma unroll
        for (int q = 0; q < 4; ++q)
            acc[q] += s_x[(iq + q * 4) * NODE_IN + k] * wv;
    }
#pragma unroll
    for (int q = 0; q < 4; ++q) {
        int n = n0 + iq + q * 4;
        float v = fmaxf(acc[q], 0.f);
        hout[(size_t)n * 64 + j] = v;
        hb[(size_t)n * 64 + j] = f2bf(v);
    }
}

// ---------------------------------------------------------------------------
// Edge MLP via bf16 MFMA + scatter-add. 64-edge tiles, 4 waves x 16 edges.
// All per-tile LDS is wave-private -> no __syncthreads in the main loop.
// ---------------------------------------------------------------------------
__global__ __launch_bounds__(256, 2)
void edge_mlp_mfma(const short* __restrict__ hb,
                   const int* __restrict__ src_idx,
                   const int* __restrict__ dst_idx,
                   const float* __restrict__ eattr,
                   const float* __restrict__ we, const float* __restrict__ be,
                   const float* __restrict__ w1, const float* __restrict__ b1,
                   const float* __restrict__ w2, const float* __restrict__ b2,
                   float* __restrict__ agg)
{
    // rows of 128 bf16 = 16 slots of 16B, slot XOR-swizzled by (row&7)
    __shared__ __align__(16) short s_w1t[128 * 128]; // W1^T [j][k]
    __shared__ __align__(16) short s_w2t[64 * 128];  // W2^T [j][k]
    __shared__ __align__(16) short s_mi[64 * 128];   // m_in tile / hidden tile
    __shared__ __align__(16) short s_ei[64 * 32];    // edge_attr bf16, k>=16 zero
    __shared__ __align__(16) short s_wet[64 * 32];   // we^T [j][k], k>=16 zero
    __shared__ float s_b1f[128];
    __shared__ float s_b2f[64];
    __shared__ float s_bef[64];

    const int t = threadIdx.x;

    // ---- one-time weight staging ----
    for (int c = t; c < 128 * 16; c += 256) {          // W1^T
        int k = c & 127, j8 = c >> 7;
        const float4* wp = (const float4*)(w1 + (size_t)k * 128 + j8 * 8);
        float4 x0 = wp[0], x1 = wp[1];
        short vals[8] = { f2bf(x0.x), f2bf(x0.y), f2bf(x0.z), f2bf(x0.w),
                          f2bf(x1.x), f2bf(x1.y), f2bf(x1.z), f2bf(x1.w) };
        int slot = k >> 3, kin = k & 7;
#pragma unroll
        for (int u = 0; u < 8; ++u) {
            int row = j8 * 8 + u;
            s_w1t[row * 128 + ((slot ^ (row & 7)) << 3) + kin] = vals[u];
        }
    }
    for (int c = t; c < 128 * 8; c += 256) {           // W2^T
        int k = c & 127, j8 = c >> 7;
        const float4* wp = (const float4*)(w2 + (size_t)k * 64 + j8 * 8);
        float4 x0 = wp[0], x1 = wp[1];
        short vals[8] = { f2bf(x0.x), f2bf(x0.y), f2bf(x0.z), f2bf(x0.w),
                          f2bf(x1.x), f2bf(x1.y), f2bf(x1.z), f2bf(x1.w) };
        int slot = k >> 3, kin = k & 7;
#pragma unroll
        for (int u = 0; u < 8; ++u) {
            int row = j8 * 8 + u;
            s_w2t[row * 128 + ((slot ^ (row & 7)) << 3) + kin] = vals[u];
        }
    }
    for (int idx = t; idx < 64 * 32; idx += 256) s_wet[idx] = 0;
    for (int idx = t; idx < 64 * 16; idx += 256)        // zero pad of s_ei
        s_ei[(idx >> 4) * 32 + 16 + (idx & 15)] = 0;
    __syncthreads();
    for (int idx = t; idx < 16 * 64; idx += 256) {      // we^T fill (k<16)
        int k = idx & 15, jj = idx >> 4;
        s_wet[jj * 32 + k] = f2bf(we[k * 64 + jj]);
    }
    if (t < 128) s_b1f[t] = b1[t];
    if (t < 64) { s_b2f[t] = b2[t]; s_bef[t] = be[t]; }
    __syncthreads();

    const int w  = t >> 6;        // wave id (owns edges 16w..16w+15 of tile)
    const int l  = t & 63;        // lane
    const int rl = l & 15;        // fragment row/col index
    const int hi = l >> 4;        // k-group / C-row-block index

    for (int tile = blockIdx.x; tile < N_EDGES / 64; tile += gridDim.x) {
        const int e0 = tile * 64;

        // ---- stage m_in h-part + edge_attr (wave-local rows) ----
        {
            const int e_loc = (w << 4) + (l >> 2);
            const int e = e0 + e_loc;
            const int part = l & 3;
            if (part < 2) {
                int sn = src_idx[e];
                const int4* hp = (const int4*)(hb + (size_t)sn * 64 + part * 32);
#pragma unroll
                for (int c = 0; c < 4; ++c) {
                    int4 v = hp[c];
                    int slot = part * 4 + c;
                    *(int4*)&s_mi[e_loc * 128 + ((slot ^ (e_loc & 7)) << 3)] = v;
                }
            } else {
                int q = part & 1;
                const float4* ap = (const float4*)(eattr + (size_t)e * 16 + q * 8);
                float4 v0 = ap[0], v1 = ap[1];
                union { short s[8]; int4 v; } u;
                u.s[0] = f2bf(v0.x); u.s[1] = f2bf(v0.y);
                u.s[2] = f2bf(v0.z); u.s[3] = f2bf(v0.w);
                u.s[4] = f2bf(v1.x); u.s[5] = f2bf(v1.y);
                u.s[6] = f2bf(v1.z); u.s[7] = f2bf(v1.w);
                *(int4*)&s_ei[e_loc * 32 + q * 8] = u.v;
            }
        }
        __builtin_amdgcn_wave_barrier();
        __builtin_amdgcn_sched_barrier(0);

        // ---- edge embedding: ea = relu(edge_attr @ we + be) -> m_in cols 64..127
        {
            const int arow = w * 16 + rl;
            bf16x8 ea_a = *(const bf16x8*)&s_ei[arow * 32 + hi * 8];
#pragma unroll
            for (int n = 0; n < 4; ++n) {
                int jrow = n * 16 + rl;
                bf16x8 bfr = *(const bf16x8*)&s_wet[jrow * 32 + hi * 8];
                float bj = s_bef[jrow];
                f32x4 c = { bj, bj, bj, bj };
                c = MFMA16(ea_a, bfr, c);
#pragma unroll
                for (int r = 0; r < 4; ++r) {
                    int row = w * 16 + hi * 4 + r;
                    int col = 64 + n * 16 + rl;
                    int slot = col >> 3;
                    s_mi[row * 128 + ((slot ^ (row & 7)) << 3) + (col & 7)] =
                        f2bf(fmaxf(c[r], 0.f));
                }
            }
        }
        __builtin_amdgcn_wave_barrier();
        __builtin_amdgcn_sched_barrier(0);

        // ---- GEMM1: hidden = relu(m_in @ W1 + b1) (A-frags preloaded) ----
        {
            const int arow = w * 16 + rl;
            bf16x8 a1[4];
#pragma unroll
            for (int s = 0; s < 4; ++s)
                a1[s] = *(const bf16x8*)&s_mi[arow * 128 + (((4 * s + hi) ^ (arow & 7)) << 3)];
            __builtin_amdgcn_wave_barrier();   // all A reads before hid overwrite
#pragma unroll
            for (int n = 0; n < 8; ++n) {
                int jrow = n * 16 + rl;
                float bj = s_b1f[jrow];
                f32x4 c = { bj, bj, bj, bj };
#pragma unroll
                for (int s = 0; s < 4; ++s) {
                    bf16x8 bfr = *(const bf16x8*)&s_w1t[jrow * 128 + (((4 * s + hi) ^ (jrow & 7)) << 3)];
                    c = MFMA16(a1[s], bfr, c);
                }
#pragma unroll
                for (int r = 0; r < 4; ++r) {
                    int row = w * 16 + hi * 4 + r;
                    int col = n * 16 + rl;
                    int slot = col >> 3;
                    s_mi[row * 128 + ((slot ^ (row & 7)) << 3) + (col & 7)] =
                        f2bf(fmaxf(c[r], 0.f));
                }
            }
        }
        __builtin_amdgcn_wave_barrier();
        __builtin_amdgcn_sched_barrier(0);

        // ---- GEMM2: m = hidden @ W2 + b2, scatter-add to agg ----
        {
            const int arow = w * 16 + rl;
            bf16x8 a2[4];
#pragma unroll
            for (int s = 0; s < 4; ++s)
                a2[s] = *(const bf16x8*)&s_mi[arow * 128 + (((4 * s + hi) ^ (arow & 7)) << 3)];
            int4 dvec = *(const int4*)(dst_idx + e0 + w * 16 + hi * 4);
            int dst4[4] = { dvec.x, dvec.y, dvec.z, dvec.w };
#pragma unroll
            for (int n = 0; n < 4; ++n) {
                int jrow = n * 16 + rl;
                float bj = s_b2f[jrow];
                f32x4 c = { bj, bj, bj, bj };
#pragma unroll
                for (int s = 0; s < 4; ++s) {
                    bf16x8 bfr = *(const bf16x8*)&s_w2t[jrow * 128 + (((4 * s + hi) ^ (jrow & 7)) << 3)];
                    c = MFMA16(a2[s], bfr, c);
                }
#pragma unroll
                for (int r = 0; r < 4; ++r)
                    atomicAdd(agg + (size_t)dst4[r] * 64 + n * 16 + rl, c[r]);
            }
        }
        __builtin_amdgcn_wave_barrier();
        __builtin_amdgcn_sched_barrier(0);
    }
}

// ---------------------------------------------------------------------------
// Self update: h2 = relu(agg + h @ self_w + self_b); writes f32 + bf16
// ---------------------------------------------------------------------------
__global__ __launch_bounds__(256)
void self_update_kernel(const float* __restrict__ hin, const float* __restrict__ agg,
                        const float* __restrict__ sw, const float* __restrict__ sb,
                        float* __restrict__ hout, short* __restrict__ hb)
{
    __shared__ float s_h[16 * 64];
    const int t = threadIdx.x;
    const int j = t & 63, iq = t >> 6;
    const int n0 = blockIdx.x * 16;

    for (int idx = t; idx < 16 * 64; idx += 256)
        s_h[idx] = hin[(size_t)n0 * 64 + idx];
    __syncthreads();

    float acc[4];
    const float bj = sb[j];
#pragma unroll
    for (int q = 0; q < 4; ++q) acc[q] = bj;

#pragma unroll 4
    for (int k = 0; k < 64; ++k) {
        float wv = sw[k * 64 + j];
#pragma unroll
        for (int q = 0; q < 4; ++q)
            acc[q] += s_h[(iq + q * 4) * 64 + k] * wv;
    }
#pragma unroll
    for (int q = 0; q < 4; ++q) {
        int n = n0 + iq + q * 4;
        float v = fmaxf(acc[q] + agg[(size_t)n * 64 + j], 0.f);
        hout[(size_t)n * 64 + j] = v;
        hb[(size_t)n * 64 + j] = f2bf(v);
    }
}

// ---------------------------------------------------------------------------
// Graph pooling (batch sorted; run-length pre-reduction, then atomics)
// ---------------------------------------------------------------------------
__global__ __launch_bounds__(256)
void pool_kernel(const float* __restrict__ h, const int* __restrict__ batch,
                 float* __restrict__ gsum, float* __restrict__ counts)
{
    const int t = threadIdx.x;
    const int j = t & 63, ty = t >> 6;
    const int grp = blockIdx.x * 4 + ty;
    if (grp >= N_NODES / 32) return;
    const int n0 = grp * 32;

    float acc = 0.f, cnt = 0.f;
    int cur = batch[n0];
    for (int n = n0; n < n0 + 32; ++n) {
        int b = batch[n];
        if (b != cur) {
            atomicAdd(gsum + (size_t)cur * 64 + j, acc);
            if (j == 0) atomicAdd(counts + cur, cnt);
            acc = 0.f; cnt = 0.f; cur = b;
        }
        acc += h[(size_t)n * 64 + j];
        cnt += 1.f;
    }
    atomicAdd(gsum + (size_t)cur * 64 + j, acc);
    if (j == 0) atomicAdd(counts + cur, cnt);
}

// ---------------------------------------------------------------------------
// Readout
// ---------------------------------------------------------------------------
__global__ __launch_bounds__(64)
void readout_kernel(const float* __restrict__ gsum, const float* __restrict__ counts,
                    const float* __restrict__ w1, const float* __restrict__ b1,
                    const float* __restrict__ w2, const float* __restrict__ b2,
                    float* __restrict__ out)
{
    __shared__ float s_g[128];
    const int g = blockIdx.x, t = threadIdx.x;
    float sv = gsum[(size_t)g * 64 + t];
    float c = fmaxf(counts[g], 1.f);
    s_g[t] = sv;
    s_g[64 + t] = sv / c;
    __syncthreads();

    float acc = b1[t];
#pragma unroll 4
    for (int k = 0; k < 128; ++k)
        acc += s_g[k] * w1[k * 64 + t];
    acc = fmaxf(acc, 0.f);

    float p = acc * w2[t];
#pragma unroll
    for (int m = 1; m < 64; m <<= 1)
        p += __shfl_xor(p, m, 64);
    if (t == 0) out[g] = p + b2[0];
}

// ---------------------------------------------------------------------------
extern "C" void kernel_launch(void* const* d_in, const int* in_sizes, int n_in,
                              void* d_out, int out_size, void* d_ws, size_t ws_size,
                              hipStream_t stream)
{
    const float* x      = (const float*)d_in[0];
    const int*   eidx   = (const int*)d_in[1];
    const float* eattr  = (const float*)d_in[2];
    const int*   batch  = (const int*)d_in[3];
    const float* node_w = (const float*)d_in[4];
    const float* node_b = (const float*)d_in[5];
    const float* edge_w = (const float*)d_in[6];
    const float* edge_b = (const float*)d_in[7];
    const float* msg_w1 = (const float*)d_in[8];
    const float* msg_b1 = (const float*)d_in[9];
    const float* msg_w2 = (const float*)d_in[10];
    const float* msg_b2 = (const float*)d_in[11];
    const float* self_w = (const float*)d_in[12];
    const float* self_b = (const float*)d_in[13];
    const float* ro_w1  = (const float*)d_in[14];
    const float* ro_b1  = (const float*)d_in[15];
    const float* ro_w2  = (const float*)d_in[16];
    const float* ro_b2  = (const float*)d_in[17];
    float* out = (float*)d_out;

    char* ws = (char*)d_ws;
    float* h0     = (float*)ws;                                    ws += (size_t)N_NODES * 64 * 4;
    float* h1     = (float*)ws;                                    ws += (size_t)N_NODES * 64 * 4;
    float* agg    = (float*)ws;                                    ws += (size_t)N_NODES * 64 * 4;
    short* hb0    = (short*)ws;                                    ws += (size_t)N_NODES * 64 * 2;
    short* hb1    = (short*)ws;                                    ws += (size_t)N_NODES * 64 * 2;
    float* gsum   = (float*)ws;                                    ws += (size_t)N_GRAPH * 64 * 4;
    float* counts = (float*)ws;

    const int* srcp = eidx;
    const int* dstp = eidx + N_EDGES;

    node_embed_kernel<<<N_NODES / 16, 256, 0, stream>>>(x, node_w, node_b, h0, hb0);

    float* hc = h0;  float* hn = h1;
    short* hbc = hb0; short* hbn = hb1;
    for (int l = 0; l < NLAYER; ++l) {
        hipMemsetAsync(agg, 0, (size_t)N_NODES * 64 * sizeof(float), stream);
        edge_mlp_mfma<<<EDGE_GRID, 256, 0, stream>>>(
            hbc, srcp, dstp, eattr, edge_w, edge_b,
            msg_w1 + (size_t)l * 128 * 128, msg_b1 + (size_t)l * 128,
            msg_w2 + (size_t)l * 128 * 64,  msg_b2 + (size_t)l * 64,
            agg);
        self_update_kernel<<<N_NODES / 16, 256, 0, stream>>>(
            hc, agg, self_w + (size_t)l * 64 * 64, self_b + (size_t)l * 64, hn, hbn);
        float* tf = hc; hc = hn; hn = tf;
        short* tb = hbc; hbc = hbn; hbn = tb;
    }

    hipMemsetAsync(gsum, 0, (size_t)(N_GRAPH * 64 + N_GRAPH) * sizeof(float), stream);
    pool_kernel<<<(N_NODES / 32 + 3) / 4, 256, 0, stream>>>(hc, batch, gsum, counts);
    readout_kernel<<<N_GRAPH, 64, 0, stream>>>(gsum, counts, ro_w1, ro_b1, ro_w2, ro_b2, out);
}

// Round 3
// 624.672 us; speedup vs baseline: 4.5442x; 1.1522x over previous
//
#include <hip/hip_runtime.h>

#define N_NODES 100000
#define N_EDGES 800000
#define N_GRAPH 512
#define NODE_IN 92
#define NLAYER 3
#define EDGE_GRID 1024
#define NCHUNK 98           // ceil(100001/1024)
#define CNTPAD 100352       // 98*1024

typedef short bf16x8 __attribute__((ext_vector_type(8)));
typedef float f32x4  __attribute__((ext_vector_type(4)));

#define MFMA16(a, b, c) __builtin_amdgcn_mfma_f32_16x16x32_bf16(a, b, c, 0, 0, 0)

__device__ __forceinline__ short f2bf(float f) {
    union { float f; unsigned u; } v; v.f = f;
    unsigned u = v.u;
    unsigned r = (u + 0x7fffu + ((u >> 16) & 1u)) >> 16;
    return (short)r;
}

// ---------------------------------------------------------------------------
// Node embedding: h = relu(x @ node_w + node_b); writes f32 + bf16 copies
// ---------------------------------------------------------------------------
__global__ __launch_bounds__(256)
void node_embed_kernel(const float* __restrict__ x, const float* __restrict__ nw,
                       const float* __restrict__ nb, float* __restrict__ hout,
                       short* __restrict__ hb)
{
    __shared__ float s_x[16 * NODE_IN];
    const int t = threadIdx.x;
    const int j = t & 63, iq = t >> 6;
    const int n0 = blockIdx.x * 16;

    for (int idx = t; idx < 16 * NODE_IN; idx += 256)
        s_x[idx] = x[(size_t)n0 * NODE_IN + idx];
    __syncthreads();

    float acc[4];
    const float bj = nb[j];
#pragma unroll
    for (int q = 0; q < 4; ++q) acc[q] = bj;

#pragma unroll 4
    for (int k = 0; k < NODE_IN; ++k) {
        float wv = nw[k * 64 + j];
#pragma unroll
        for (int q = 0; q < 4; ++q)
            acc[q] += s_x[(iq + q * 4) * NODE_IN + k] * wv;
    }
#pragma unroll
    for (int q = 0; q < 4; ++q) {
        int n = n0 + iq + q * 4;
        float v = fmaxf(acc[q], 0.f);
        hout[(size_t)n * 64 + j] = v;
        hb[(size_t)n * 64 + j] = f2bf(v);
    }
}

// ---------------------------------------------------------------------------
// Counting sort of edges by dst: histogram -> scan -> scatter-permute
// ---------------------------------------------------------------------------
__global__ __launch_bounds__(256)
void hist_kernel(const int* __restrict__ dst, int* __restrict__ cnt)
{
    int e = blockIdx.x * 256 + threadIdx.x;
    if (e < N_EDGES) atomicAdd(&cnt[dst[e] + 1], 1);
}

__global__ __launch_bounds__(256)
void scan_chunk_sums(const int* __restrict__ cnt, int* __restrict__ bsums)
{
    __shared__ int s[256];
    const int b = blockIdx.x, t = threadIdx.x;
    int base = b * 1024 + t * 4, v = 0;
#pragma unroll
    for (int k = 0; k < 4; ++k) {
        int idx = base + k;
        if (idx < N_NODES + 1) v += cnt[idx];
    }
    s[t] = v; __syncthreads();
    for (int off = 128; off > 0; off >>= 1) {
        if (t < off) s[t] += s[t + off];
        __syncthreads();
    }
    if (t == 0) bsums[b] = s[0];
}

__global__ void scan_bsums(int* __restrict__ bsums)
{
    if (threadIdx.x == 0 && blockIdx.x == 0) {
        int run = 0;
        for (int i = 0; i < NCHUNK; ++i) { int v = bsums[i]; bsums[i] = run; run += v; }
    }
}

__global__ __launch_bounds__(1024)
void scan_apply(int* __restrict__ cnt, const int* __restrict__ bsums)
{
    __shared__ int s[1024];
    const int b = blockIdx.x, t = threadIdx.x;
    const int idx = b * 1024 + t;
    int v = (idx < N_NODES + 1) ? cnt[idx] : 0;
    s[t] = v; __syncthreads();
    for (int off = 1; off < 1024; off <<= 1) {
        int x = (t >= off) ? s[t - off] : 0;
        __syncthreads();
        s[t] += x;
        __syncthreads();
    }
    if (idx < N_NODES + 1) cnt[idx] = s[t] + bsums[b];
}

__global__ __launch_bounds__(256)
void scatter_kernel(const int* __restrict__ src, const int* __restrict__ dst,
                    const float* __restrict__ eattr,
                    const int* __restrict__ off, int* __restrict__ pos,
                    int* __restrict__ src_p, int* __restrict__ dst_p,
                    short* __restrict__ ea_p)
{
    int e = blockIdx.x * 256 + threadIdx.x;
    if (e >= N_EDGES) return;
    int d = dst[e];
    int p = off[d] + atomicAdd(&pos[d], 1);
    src_p[p] = src[e];
    dst_p[p] = d;
    const float4* ap = (const float4*)(eattr + (size_t)e * 16);
    float4 v0 = ap[0], v1 = ap[1], v2 = ap[2], v3 = ap[3];
    union { short s[16]; int4 v[2]; } u;
    u.s[0] = f2bf(v0.x); u.s[1] = f2bf(v0.y); u.s[2]  = f2bf(v0.z); u.s[3]  = f2bf(v0.w);
    u.s[4] = f2bf(v1.x); u.s[5] = f2bf(v1.y); u.s[6]  = f2bf(v1.z); u.s[7]  = f2bf(v1.w);
    u.s[8] = f2bf(v2.x); u.s[9] = f2bf(v2.y); u.s[10] = f2bf(v2.z); u.s[11] = f2bf(v2.w);
    u.s[12]= f2bf(v3.x); u.s[13]= f2bf(v3.y); u.s[14] = f2bf(v3.z); u.s[15] = f2bf(v3.w);
    *(int4*)(ea_p + (size_t)p * 16)     = u.v[0];
    *(int4*)(ea_p + (size_t)p * 16 + 8) = u.v[1];
}

// ---------------------------------------------------------------------------
// Edge MLP via bf16 MFMA on dst-sorted edges + in-LDS segment reduction.
// 64-edge tiles, 4 waves x 16 edges, wave-private LDS -> no block barriers.
// ---------------------------------------------------------------------------
__global__ __launch_bounds__(256, 2)
void edge_mlp_mfma(const short* __restrict__ hb,
                   const int* __restrict__ src_p,
                   const int* __restrict__ dst_p,
                   const short* __restrict__ ea_p,
                   const float* __restrict__ we, const float* __restrict__ be,
                   const float* __restrict__ w1, const float* __restrict__ b1,
                   const float* __restrict__ w2, const float* __restrict__ b2,
                   float* __restrict__ agg)
{
    __shared__ __align__(16) short s_w1t[128 * 128]; // W1^T [j][k] swizzled
    __shared__ __align__(16) short s_w2t[64 * 128];  // W2^T [j][k] swizzled
    __shared__ __align__(16) short s_mi[64 * 128];   // m_in / hidden / f32 reduce
    __shared__ __align__(16) short s_ei[64 * 32];    // ea bf16, k>=16 zero
    __shared__ __align__(16) short s_wet[64 * 32];   // we^T [j][k], k>=16 zero
    __shared__ float s_b1f[128];
    __shared__ float s_b2f[64];
    __shared__ float s_bef[64];
    __shared__ int   s_dst[64];

    const int t = threadIdx.x;

    // ---- one-time weight staging ----
    for (int c = t; c < 128 * 16; c += 256) {          // W1^T
        int k = c & 127, j8 = c >> 7;
        const float4* wp = (const float4*)(w1 + (size_t)k * 128 + j8 * 8);
        float4 x0 = wp[0], x1 = wp[1];
        short vals[8] = { f2bf(x0.x), f2bf(x0.y), f2bf(x0.z), f2bf(x0.w),
                          f2bf(x1.x), f2bf(x1.y), f2bf(x1.z), f2bf(x1.w) };
        int slot = k >> 3, kin = k & 7;
#pragma unroll
        for (int u = 0; u < 8; ++u) {
            int row = j8 * 8 + u;
            s_w1t[row * 128 + ((slot ^ (row & 7)) << 3) + kin] = vals[u];
        }
    }
    for (int c = t; c < 128 * 8; c += 256) {           // W2^T
        int k = c & 127, j8 = c >> 7;
        const float4* wp = (const float4*)(w2 + (size_t)k * 64 + j8 * 8);
        float4 x0 = wp[0], x1 = wp[1];
        short vals[8] = { f2bf(x0.x), f2bf(x0.y), f2bf(x0.z), f2bf(x0.w),
                          f2bf(x1.x), f2bf(x1.y), f2bf(x1.z), f2bf(x1.w) };
        int slot = k >> 3, kin = k & 7;
#pragma unroll
        for (int u = 0; u < 8; ++u) {
            int row = j8 * 8 + u;
            s_w2t[row * 128 + ((slot ^ (row & 7)) << 3) + kin] = vals[u];
        }
    }
    for (int idx = t; idx < 64 * 32; idx += 256) s_wet[idx] = 0;
    for (int idx = t; idx < 64 * 16; idx += 256)        // zero pad of s_ei
        s_ei[(idx >> 4) * 32 + 16 + (idx & 15)] = 0;
    __syncthreads();
    for (int idx = t; idx < 16 * 64; idx += 256) {      // we^T fill (k<16)
        int k = idx & 15, jj = idx >> 4;
        s_wet[jj * 32 + k] = f2bf(we[k * 64 + jj]);
    }
    if (t < 128) s_b1f[t] = b1[t];
    if (t < 64) { s_b2f[t] = b2[t]; s_bef[t] = be[t]; }
    __syncthreads();

    const int w  = t >> 6;        // wave id (owns edges 16w..16w+15 of tile)
    const int l  = t & 63;        // lane
    const int rl = l & 15;
    const int hi = l >> 4;
    const int e_loc = (w << 4) + (l >> 2);
    const int part  = l & 3;

    for (int tile = blockIdx.x; tile < N_EDGES / 64; tile += gridDim.x) {
        const int e0 = tile * 64;
        const int e  = e0 + e_loc;

        // ---- stage (wave-private): dsts, gathered h, permuted ea ----
        if (l < 16) s_dst[w * 16 + l] = dst_p[e0 + w * 16 + l];
        if (part < 2) {
            int sn = src_p[e];
            const int4* hp = (const int4*)(hb + (size_t)sn * 64 + part * 32);
#pragma unroll
            for (int c = 0; c < 4; ++c) {
                int4 v = hp[c];
                int slot = part * 4 + c;
                *(int4*)&s_mi[e_loc * 128 + ((slot ^ (e_loc & 7)) << 3)] = v;
            }
        } else if (part == 2) {
            const int4* ap = (const int4*)(ea_p + (size_t)e * 16);
            int4 v0 = ap[0], v1 = ap[1];
            *(int4*)&s_ei[e_loc * 32]     = v0;
            *(int4*)&s_ei[e_loc * 32 + 8] = v1;
        }

        // ---- edge embedding: ea=relu(eattr@we+be) -> m_in cols 64..127 ----
        {
            const int arow = w * 16 + rl;
            bf16x8 ea_a = *(const bf16x8*)&s_ei[arow * 32 + hi * 8];
#pragma unroll
            for (int n = 0; n < 4; ++n) {
                int jrow = n * 16 + rl;
                bf16x8 bfr = *(const bf16x8*)&s_wet[jrow * 32 + hi * 8];
                float bj = s_bef[jrow];
                f32x4 c = { bj, bj, bj, bj };
                c = MFMA16(ea_a, bfr, c);
#pragma unroll
                for (int r = 0; r < 4; ++r) {
                    int row = w * 16 + hi * 4 + r;
                    int col = 64 + n * 16 + rl;
                    int slot = col >> 3;
                    s_mi[row * 128 + ((slot ^ (row & 7)) << 3) + (col & 7)] =
                        f2bf(fmaxf(c[r], 0.f));
                }
            }
        }

        // ---- GEMM1: hidden = relu(m_in @ W1 + b1) ----
        {
            const int arow = w * 16 + rl;
            bf16x8 a1[4];
#pragma unroll
            for (int s = 0; s < 4; ++s)
                a1[s] = *(const bf16x8*)&s_mi[arow * 128 + (((4 * s + hi) ^ (arow & 7)) << 3)];
#pragma unroll
            for (int n = 0; n < 8; ++n) {
                int jrow = n * 16 + rl;
                float bj = s_b1f[jrow];
                f32x4 c = { bj, bj, bj, bj };
#pragma unroll
                for (int s = 0; s < 4; ++s) {
                    bf16x8 bfr = *(const bf16x8*)&s_w1t[jrow * 128 + (((4 * s + hi) ^ (jrow & 7)) << 3)];
                    c = MFMA16(a1[s], bfr, c);
                }
#pragma unroll
                for (int r = 0; r < 4; ++r) {
                    int row = w * 16 + hi * 4 + r;
                    int col = n * 16 + rl;
                    int slot = col >> 3;
                    s_mi[row * 128 + ((slot ^ (row & 7)) << 3) + (col & 7)] =
                        f2bf(fmaxf(c[r], 0.f));
                }
            }
        }

        // ---- GEMM2: m = hidden @ W2 + b2 -> f32 frags into wave's LDS ----
        {
            const int arow = w * 16 + rl;
            bf16x8 a2[4];
#pragma unroll
            for (int s = 0; s < 4; ++s)
                a2[s] = *(const bf16x8*)&s_mi[arow * 128 + (((4 * s + hi) ^ (arow & 7)) << 3)];
            float* s_red = (float*)&s_mi[w * 16 * 128];   // 16x64 f32, wave region
#pragma unroll
            for (int n = 0; n < 4; ++n) {
                int jrow = n * 16 + rl;
                float bj = s_b2f[jrow];
                f32x4 c = { bj, bj, bj, bj };
#pragma unroll
                for (int s = 0; s < 4; ++s) {
                    bf16x8 bfr = *(const bf16x8*)&s_w2t[jrow * 128 + (((4 * s + hi) ^ (jrow & 7)) << 3)];
                    c = MFMA16(a2[s], bfr, c);
                }
#pragma unroll
                for (int r = 0; r < 4; ++r)
                    s_red[(hi * 4 + r) * 64 + n * 16 + rl] = c[r];
            }
        }

        // ---- segmented reduce over the wave's 16 sorted edges ----
        {
            const float* s_red = (const float*)&s_mi[w * 16 * 128];
            float acc = 0.f;
            int cur = s_dst[w * 16];
            bool first = true;
            for (int r = 0; r < 16; ++r) {
                int d = s_dst[w * 16 + r];
                if (d != cur) {
                    float* ap2 = agg + (size_t)cur * 64 + l;
                    if (first) atomicAdd(ap2, acc);
                    else       *ap2 = acc;           // interior run: exclusive
                    first = false; acc = 0.f; cur = d;
                }
                acc += s_red[r * 64 + l];
            }
            atomicAdd(agg + (size_t)cur * 64 + l, acc);  // touches window end
        }
    }
}

// ---------------------------------------------------------------------------
// Self update (in place): h = relu(agg + h @ self_w + self_b); refresh hb
// ---------------------------------------------------------------------------
__global__ __launch_bounds__(256)
void self_update_kernel(float* h, short* hb, const float* __restrict__ agg,
                        const float* __restrict__ sw, const float* __restrict__ sb)
{
    __shared__ float s_h[16 * 64];
    const int t = threadIdx.x;
    const int j = t & 63, iq = t >> 6;
    const int n0 = blockIdx.x * 16;

    for (int idx = t; idx < 16 * 64; idx += 256)
        s_h[idx] = h[(size_t)n0 * 64 + idx];
    __syncthreads();

    float acc[4];
    const float bj = sb[j];
#pragma unroll
    for (int q = 0; q < 4; ++q) acc[q] = bj;

#pragma unroll 4
    for (int k = 0; k < 64; ++k) {
        float wv = sw[k * 64 + j];
#pragma unroll
        for (int q = 0; q < 4; ++q)
            acc[q] += s_h[(iq + q * 4) * 64 + k] * wv;
    }
#pragma unroll
    for (int q = 0; q < 4; ++q) {
        int n = n0 + iq + q * 4;
        float v = fmaxf(acc[q] + agg[(size_t)n * 64 + j], 0.f);
        h[(size_t)n * 64 + j] = v;
        hb[(size_t)n * 64 + j] = f2bf(v);
    }
}

// ---------------------------------------------------------------------------
// Graph pooling (batch sorted; run-length pre-reduction, then atomics)
// ---------------------------------------------------------------------------
__global__ __launch_bounds__(256)
void pool_kernel(const float* __restrict__ h, const int* __restrict__ batch,
                 float* __restrict__ gsum, float* __restrict__ counts)
{
    const int t = threadIdx.x;
    const int j = t & 63, ty = t >> 6;
    const int grp = blockIdx.x * 4 + ty;
    if (grp >= N_NODES / 32) return;
    const int n0 = grp * 32;

    float acc = 0.f, cnt = 0.f;
    int cur = batch[n0];
    for (int n = n0; n < n0 + 32; ++n) {
        int b = batch[n];
        if (b != cur) {
            atomicAdd(gsum + (size_t)cur * 64 + j, acc);
            if (j == 0) atomicAdd(counts + cur, cnt);
            acc = 0.f; cnt = 0.f; cur = b;
        }
        acc += h[(size_t)n * 64 + j];
        cnt += 1.f;
    }
    atomicAdd(gsum + (size_t)cur * 64 + j, acc);
    if (j == 0) atomicAdd(counts + cur, cnt);
}

// ---------------------------------------------------------------------------
// Readout
// ---------------------------------------------------------------------------
__global__ __launch_bounds__(64)
void readout_kernel(const float* __restrict__ gsum, const float* __restrict__ counts,
                    const float* __restrict__ w1, const float* __restrict__ b1,
                    const float* __restrict__ w2, const float* __restrict__ b2,
                    float* __restrict__ out)
{
    __shared__ float s_g[128];
    const int g = blockIdx.x, t = threadIdx.x;
    float sv = gsum[(size_t)g * 64 + t];
    float c = fmaxf(counts[g], 1.f);
    s_g[t] = sv;
    s_g[64 + t] = sv / c;
    __syncthreads();

    float acc = b1[t];
#pragma unroll 4
    for (int k = 0; k < 128; ++k)
        acc += s_g[k] * w1[k * 64 + t];
    acc = fmaxf(acc, 0.f);

    float p = acc * w2[t];
#pragma unroll
    for (int m = 1; m < 64; m <<= 1)
        p += __shfl_xor(p, m, 64);
    if (t == 0) out[g] = p + b2[0];
}

// ---------------------------------------------------------------------------
extern "C" void kernel_launch(void* const* d_in, const int* in_sizes, int n_in,
                              void* d_out, int out_size, void* d_ws, size_t ws_size,
                              hipStream_t stream)
{
    const float* x      = (const float*)d_in[0];
    const int*   eidx   = (const int*)d_in[1];
    const float* eattr  = (const float*)d_in[2];
    const int*   batch  = (const int*)d_in[3];
    const float* node_w = (const float*)d_in[4];
    const float* node_b = (const float*)d_in[5];
    const float* edge_w = (const float*)d_in[6];
    const float* edge_b = (const float*)d_in[7];
    const float* msg_w1 = (const float*)d_in[8];
    const float* msg_b1 = (const float*)d_in[9];
    const float* msg_w2 = (const float*)d_in[10];
    const float* msg_b2 = (const float*)d_in[11];
    const float* self_w = (const float*)d_in[12];
    const float* self_b = (const float*)d_in[13];
    const float* ro_w1  = (const float*)d_in[14];
    const float* ro_b1  = (const float*)d_in[15];
    const float* ro_w2  = (const float*)d_in[16];
    const float* ro_b2  = (const float*)d_in[17];
    float* out = (float*)d_out;

    char* wsp = (char*)d_ws;
    float* h      = (float*)wsp;                         wsp += (size_t)N_NODES * 64 * 4;
    float* agg    = (float*)wsp;                         wsp += (size_t)N_NODES * 64 * 4;
    short* hb     = (short*)wsp;                         wsp += (size_t)N_NODES * 64 * 2;
    int*   src_p  = (int*)wsp;                           wsp += (size_t)N_EDGES * 4;
    int*   dst_p  = (int*)wsp;                           wsp += (size_t)N_EDGES * 4;
    short* ea_p   = (short*)wsp;                         wsp += (size_t)N_EDGES * 16 * 2;
    float* gsum   = (float*)wsp;                         wsp += (size_t)N_GRAPH * 64 * 4;
    float* counts = (float*)wsp;

    // sort scratch aliased into agg (consumed before first agg memset)
    int* cnt   = (int*)agg;          // [CNTPAD]
    int* pos   = cnt + CNTPAD;       // [CNTPAD]
    int* bsums = pos + CNTPAD;       // [NCHUNK]

    const int* srcp = eidx;
    const int* dstp = eidx + N_EDGES;

    node_embed_kernel<<<N_NODES / 16, 256, 0, stream>>>(x, node_w, node_b, h, hb);

    // ---- one-time dst-sort of edges ----
    hipMemsetAsync(cnt, 0, (size_t)(2 * CNTPAD + 128) * sizeof(int), stream);
    hist_kernel<<<(N_EDGES + 255) / 256, 256, 0, stream>>>(dstp, cnt);
    scan_chunk_sums<<<NCHUNK, 256, 0, stream>>>(cnt, bsums);
    scan_bsums<<<1, 64, 0, stream>>>(bsums);
    scan_apply<<<NCHUNK, 1024, 0, stream>>>(cnt, bsums);
    scatter_kernel<<<(N_EDGES + 255) / 256, 256, 0, stream>>>(
        srcp, dstp, eattr, cnt, pos, src_p, dst_p, ea_p);

    for (int l = 0; l < NLAYER; ++l) {
        hipMemsetAsync(agg, 0, (size_t)N_NODES * 64 * sizeof(float), stream);
        edge_mlp_mfma<<<EDGE_GRID, 256, 0, stream>>>(
            hb, src_p, dst_p, ea_p, edge_w, edge_b,
            msg_w1 + (size_t)l * 128 * 128, msg_b1 + (size_t)l * 128,
            msg_w2 + (size_t)l * 128 * 64,  msg_b2 + (size_t)l * 64,
            agg);
        self_update_kernel<<<N_NODES / 16, 256, 0, stream>>>(
            h, hb, agg, self_w + (size_t)l * 64 * 64, self_b + (size_t)l * 64);
    }

    hipMemsetAsync(gsum, 0, (size_t)(N_GRAPH * 64 + N_GRAPH) * sizeof(float), stream);
    pool_kernel<<<(N_NODES / 32 + 3) / 4, 256, 0, stream>>>(h, batch, gsum, counts);
    readout_kernel<<<N_GRAPH, 64, 0, stream>>>(gsum, counts, ro_w1, ro_b1, ro_w2, ro_b2, out);
}